// Round 4
// baseline (230.141 us; speedup 1.0000x reference)
//
#include <hip/hip_runtime.h>
#include <math.h>

// (B,S,D,C) = (64, 576, 768, 200)
#define Bsz  64
#define Ssz  576
#define Dsz  768
#define Csz  200
#define NPAD 208        // 13 tiles of 16: 0..199 classes, col 200 = ones (rowsum), 201..207 zero
#define MT   32         // rows per wave (= per block); 576 % 32 == 0
#define NKT  12         // 768 / 64

typedef short short8 __attribute__((ext_vector_type(8)));
typedef float f32x4  __attribute__((ext_vector_type(4)));

__device__ inline unsigned short f2bf_rne(float f) {
    union { float f; unsigned int u; } v; v.f = f;
    return (unsigned short)((v.u + 0x7FFFu + ((v.u >> 16) & 1u)) >> 16);
}
// two fp32 -> packed bf16x2 (round-half-up): low16 = lo, high16 = hi
__device__ inline unsigned int pack2bf(float lo, float hi) {
    union { float f; unsigned int u; } a, b; a.f = lo; b.f = hi;
    return __builtin_amdgcn_perm(b.u + 0x8000u, a.u + 0x8000u, 0x07060302u);
}

// one-time: W (200x768 fp32) -> bf16 (208x768); row 200 = 1.0 (rowsum trick), 201..207 = 0
__global__ __launch_bounds__(256) void prep_w(const float* __restrict__ W,
                                              unsigned short* __restrict__ Wb) {
    const int i   = blockIdx.x * 256 + threadIdx.x;
    const int row = i / (Dsz / 4);
    const int col = (i % (Dsz / 4)) * 4;
    ushort4 h;
    if (row < Csz) {
        const float4 v = *(const float4*)(W + (size_t)row * Dsz + col);
        h.x = f2bf_rne(v.x); h.y = f2bf_rne(v.y); h.z = f2bf_rne(v.z); h.w = f2bf_rne(v.w);
    } else if (row == Csz) {
        h.x = h.y = h.z = h.w = 0x3F80;   // bf16 1.0
    } else {
        h.x = h.y = h.z = h.w = 0;
    }
    *(ushort4*)(Wb + (size_t)row * Dsz + col) = h;
}

// global classifier runs FIRST: out[b,c] = ct[b]·gw[c] + gb[c]
__global__ __launch_bounds__(256) void gc_kernel(
    const float* __restrict__ ct, const float* __restrict__ gw,
    const float* __restrict__ gb, float* __restrict__ out) {
    const int b    = blockIdx.x;
    const int wv   = threadIdx.x >> 6;
    const int lane = threadIdx.x & 63;
    const int c    = blockIdx.y * 4 + wv;
    const float* wr = gw + (size_t)c * Dsz + lane * 12;
    const float* cr = ct + (size_t)b * Dsz + lane * 12;
    float s = 0.f;
#pragma unroll
    for (int j = 0; j < 3; ++j) {
        const float4 w = *(const float4*)(wr + 4 * j);
        const float4 x = *(const float4*)(cr + 4 * j);
        s += w.x * x.x + w.y * x.y + w.z * x.z + w.w * x.w;
    }
#pragma unroll
    for (int off = 32; off > 0; off >>= 1) s += __shfl_down(s, off, 64);
    if (lane == 0) out[b * Csz + c] = s + gb[c];
}

// One wave per block, 32 rows per wave, NO LDS, NO barriers.
// A direct from global w/ next-iter reg prefetch; B direct from global (L2-resident W).
// Epilogue atomically adds lam * sigmoid-weighted rowsum contribution into out.
__global__ __launch_bounds__(64, 2) void attn_kernel(
    const float* __restrict__ X,            // (B*S, D) fp32
    const unsigned short* __restrict__ Wb,  // (NPAD, D) bf16
    const float* __restrict__ attn_b,       // (C,)
    const float* __restrict__ lam,          // (1,)
    float* __restrict__ out)                // (B, C): gscore already written
{
    const int lane = threadIdx.x;
    const int m = lane & 15;
    const int q = lane >> 4;
    const int rowbase = blockIdx.x * MT;
    const int bidx    = rowbase / Ssz;      // 18 blocks per batch, never crosses

    f32x4 acc0[13], acc1[13];
#pragma unroll
    for (int t = 0; t < 13; ++t) {
        acc0[t] = (f32x4){0.f, 0.f, 0.f, 0.f};
        acc1[t] = (f32x4){0.f, 0.f, 0.f, 0.f};
    }

    // A: lane owns X row (rowbase + m) [tile0] and (+16) [tile1], k-chunk q*8 (+32 for k2=1)
    const float* xp0 = X + (size_t)(rowbase + m) * Dsz + q * 8;
    const float* xp1 = xp0 + 16 * Dsz;
    // B: lane reads Wb[t*16 + m][kt*64 + k2*32 + q*8], 16 B
    const unsigned short* wp = Wb + (size_t)m * Dsz + q * 8;

    float4 c0[4], c1[4];
    c0[0] = *(const float4*)(xp0);      c0[1] = *(const float4*)(xp0 + 4);
    c0[2] = *(const float4*)(xp0 + 32); c0[3] = *(const float4*)(xp0 + 36);
    c1[0] = *(const float4*)(xp1);      c1[1] = *(const float4*)(xp1 + 4);
    c1[2] = *(const float4*)(xp1 + 32); c1[3] = *(const float4*)(xp1 + 36);

    for (int kt = 0; kt < NKT; ++kt) {
        // prefetch next X tile (issued a full iteration ahead of use)
        const int kn = (kt + 1 < NKT) ? (kt + 1) * 64 : kt * 64;
        float4 n0[4], n1[4];
        n0[0] = *(const float4*)(xp0 + kn);      n0[1] = *(const float4*)(xp0 + kn + 4);
        n0[2] = *(const float4*)(xp0 + kn + 32); n0[3] = *(const float4*)(xp0 + kn + 36);
        n1[0] = *(const float4*)(xp1 + kn);      n1[1] = *(const float4*)(xp1 + kn + 4);
        n1[2] = *(const float4*)(xp1 + kn + 32); n1[3] = *(const float4*)(xp1 + kn + 36);

        union { short8 s; unsigned int u[4]; } a00, a01, a10, a11;
        a00.u[0] = pack2bf(c0[0].x, c0[0].y); a00.u[1] = pack2bf(c0[0].z, c0[0].w);
        a00.u[2] = pack2bf(c0[1].x, c0[1].y); a00.u[3] = pack2bf(c0[1].z, c0[1].w);
        a01.u[0] = pack2bf(c0[2].x, c0[2].y); a01.u[1] = pack2bf(c0[2].z, c0[2].w);
        a01.u[2] = pack2bf(c0[3].x, c0[3].y); a01.u[3] = pack2bf(c0[3].z, c0[3].w);
        a10.u[0] = pack2bf(c1[0].x, c1[0].y); a10.u[1] = pack2bf(c1[0].z, c1[0].w);
        a10.u[2] = pack2bf(c1[1].x, c1[1].y); a10.u[3] = pack2bf(c1[1].z, c1[1].w);
        a11.u[0] = pack2bf(c1[2].x, c1[2].y); a11.u[1] = pack2bf(c1[2].z, c1[2].w);
        a11.u[2] = pack2bf(c1[3].x, c1[3].y); a11.u[3] = pack2bf(c1[3].z, c1[3].w);

        const unsigned short* wk = wp + kt * 64;
#pragma unroll
        for (int t = 0; t < 13; ++t) {
            const short8 b0 = *(const short8*)(wk + (size_t)t * 16 * Dsz);
            acc0[t] = __builtin_amdgcn_mfma_f32_16x16x32_bf16(a00.s, b0, acc0[t], 0, 0, 0);
            acc1[t] = __builtin_amdgcn_mfma_f32_16x16x32_bf16(a10.s, b0, acc1[t], 0, 0, 0);
        }
#pragma unroll
        for (int t = 0; t < 13; ++t) {
            const short8 b1 = *(const short8*)(wk + (size_t)t * 16 * Dsz + 32);
            acc0[t] = __builtin_amdgcn_mfma_f32_16x16x32_bf16(a01.s, b1, acc0[t], 0, 0, 0);
            acc1[t] = __builtin_amdgcn_mfma_f32_16x16x32_bf16(a11.s, b1, acc1[t], 0, 0, 0);
        }
#pragma unroll
        for (int j = 0; j < 4; ++j) { c0[j] = n0[j]; c1[j] = n1[j]; }
    }

    // rowsum via ones-column (col 200 = tile 12, lanes m==8); broadcast within q-group
    float rs0[4], rs1[4];
#pragma unroll
    for (int r = 0; r < 4; ++r) {
        rs0[r] = __shfl(acc0[12][r], (lane & 48) + 8, 64);
        rs1[r] = __shfl(acc1[12][r], (lane & 48) + 8, 64);
    }
    const float scale = lam[0] * (1.f / ((float)Ssz * (float)Dsz));

    // epilogue: C/D layout col = lane&15, row = q*4 + reg. Reduce over this wave's 32 rows.
#pragma unroll
    for (int t = 0; t < 13; ++t) {
        const int c = t * 16 + m;
        if (c < Csz) {
            const float bias = attn_b[c];
            float s = 0.f;
#pragma unroll
            for (int r = 0; r < 4; ++r) {
                s += rs0[r] / (1.f + __expf(-(acc0[t][r] + bias)));
                s += rs1[r] / (1.f + __expf(-(acc1[t][r] + bias)));
            }
            s += __shfl_xor(s, 16, 64);
            s += __shfl_xor(s, 32, 64);
            if (q == 0) atomicAdd(&out[bidx * Csz + c], s * scale);
        }
    }
}

extern "C" void kernel_launch(void* const* d_in, const int* in_sizes, int n_in,
                              void* d_out, int out_size, void* d_ws, size_t ws_size,
                              hipStream_t stream) {
    const float* X   = (const float*)d_in[0];
    const float* ct  = (const float*)d_in[1];
    const float* aw  = (const float*)d_in[2];
    const float* ab  = (const float*)d_in[3];
    const float* gw  = (const float*)d_in[4];
    const float* gb  = (const float*)d_in[5];
    const float* lam = (const float*)d_in[6];
    float* out = (float*)d_out;
    unsigned short* Wb = (unsigned short*)d_ws;   // 208*768*2 = 320 KB

    prep_w<<<(NPAD * Dsz / 4) / 256, 256, 0, stream>>>(aw, Wb);
    gc_kernel<<<dim3(Bsz, Csz / 4), 256, 0, stream>>>(ct, gw, gb, out);
    attn_kernel<<<(Bsz * Ssz) / MT, 64, 0, stream>>>(X, Wb, ab, lam, out);
}